// Round 1
// baseline (230.164 us; speedup 1.0000x reference)
//
#include <hip/hip_runtime.h>
#include <hip/hip_bf16.h>
#include <stdint.h>

#define NT 512
#define NBINS 1024          // e-bits >> 20 (sign=0, 8 exp, 3 mantissa) -> max 1016
#define KMARGIN 1224        // >= 1023 (max top_k) + tie-safety margin
#define CAND_MAX 4096

__global__ __launch_bounds__(NT) void sampler_kernel(
    const float* __restrict__ logits,
    const float* __restrict__ temps,
    const float* __restrict__ minps,
    const float* __restrict__ topps,
    const int*   __restrict__ topks,
    const float* __restrict__ us,
    int* __restrict__ out, int V)
{
    const int row = blockIdx.x;
    const int tid = threadIdx.x;
    const float t = temps[row];

    __shared__ unsigned int hist[NBINS];
    __shared__ unsigned long long cand[CAND_MAX];
    __shared__ float red[NT / 64];
    __shared__ float s_m, s_denom;
    __shared__ unsigned int s_thr, s_cnt;

    for (int i = tid; i < NBINS; i += NT) hist[i] = 0u;
    if (tid == 0) s_cnt = 0u;

    const float* xrow = logits + (size_t)row * (size_t)V;
    const int n4 = V >> 2;
    const float4* x4 = (const float4*)xrow;

    // ---------------- Phase A: max of raw logits ----------------
    float lmax = -INFINITY;
    for (int i = tid; i < n4; i += NT) {
        float4 v = x4[i];
        lmax = fmaxf(lmax, fmaxf(fmaxf(v.x, v.y), fmaxf(v.z, v.w)));
    }
    for (int i = (n4 << 2) + tid; i < V; i += NT) lmax = fmaxf(lmax, xrow[i]);
    for (int off = 32; off > 0; off >>= 1) lmax = fmaxf(lmax, __shfl_xor(lmax, off));
    if ((tid & 63) == 0) red[tid >> 6] = lmax;
    __syncthreads();
    if (tid == 0) {
        float r = red[0];
        for (int w = 1; w < NT / 64; ++w) r = fmaxf(r, red[w]);
        s_m = r / t;   // == max_i(round(x_i/t)) by monotonicity of rounding
    }
    __syncthreads();
    const float m = s_m;

    // ---------------- Phase B: denom + histogram of exp bits ----------------
    float lsum = 0.f;
    for (int i = tid; i < n4; i += NT) {
        float4 v = x4[i];
        float e0 = expf(v.x / t - m);
        float e1 = expf(v.y / t - m);
        float e2 = expf(v.z / t - m);
        float e3 = expf(v.w / t - m);
        lsum += e0; lsum += e1; lsum += e2; lsum += e3;
        atomicAdd(&hist[__float_as_uint(e0) >> 20], 1u);
        atomicAdd(&hist[__float_as_uint(e1) >> 20], 1u);
        atomicAdd(&hist[__float_as_uint(e2) >> 20], 1u);
        atomicAdd(&hist[__float_as_uint(e3) >> 20], 1u);
    }
    for (int i = (n4 << 2) + tid; i < V; i += NT) {
        float e = expf(xrow[i] / t - m);
        lsum += e;
        atomicAdd(&hist[__float_as_uint(e) >> 20], 1u);
    }
    for (int off = 32; off > 0; off >>= 1) lsum += __shfl_xor(lsum, off);
    if ((tid & 63) == 0) red[tid >> 6] = lsum;
    __syncthreads();
    if (tid == 0) {
        float r = 0.f;
        for (int w = 0; w < NT / 64; ++w) r += red[w];
        s_denom = r;
    }
    __syncthreads();     // also: all histogram atomics are now visible
    const float denom = s_denom;

    // ---------------- Threshold selection (wave 0) ----------------
    if (tid < 64) {
        const int lane = tid;
        const int CH = NBINS / 64;       // 16 bins per lane
        const int base = lane * CH;
        unsigned c = 0;
        #pragma unroll
        for (int j = 0; j < CH; ++j) c += hist[base + j];
        // suffix-inclusive scan over lanes: tsuf[l] = sum_{l' >= l} c[l']
        unsigned tsuf = c;
        #pragma unroll
        for (int off = 1; off < 64; off <<= 1) {
            unsigned o = __shfl_down(tsuf, off);
            if (lane + off < 64) tsuf += o;
        }
        unsigned long long mask = __ballot(tsuf >= (unsigned)KMARGIN);
        int lstar = 63 - __builtin_clzll(mask);      // highest chunk still >= KMARGIN
        unsigned above = __shfl(tsuf, (lstar + 1) & 63);
        if (lstar == 63) above = 0u;
        if (lane == 0) {
            unsigned run = above;
            int thrbin = lstar * CH;
            for (int b = lstar * CH + CH - 1; b >= lstar * CH; --b) {
                run += hist[b];
                if (run >= (unsigned)KMARGIN) { thrbin = b; break; }
            }
            s_thr = (unsigned)thrbin << 20;
        }
    }
    __syncthreads();
    const unsigned thrkey = s_thr;

    // ---------------- Phase C: collect candidates ----------------
    for (int i = tid; i < n4; i += NT) {
        float4 v = x4[i];
        float e[4] = { expf(v.x / t - m), expf(v.y / t - m),
                       expf(v.z / t - m), expf(v.w / t - m) };
        #pragma unroll
        for (int c = 0; c < 4; ++c) {
            unsigned eb = __float_as_uint(e[c]);
            if (eb >= thrkey) {
                float p = e[c] / denom;
                unsigned pos = atomicAdd(&s_cnt, 1u);
                if (pos < CAND_MAX) {
                    unsigned idx = (unsigned)((i << 2) + c);
                    cand[pos] = ((unsigned long long)__float_as_uint(p) << 32)
                              | (unsigned)(~idx);
                }
            }
        }
    }
    for (int i = (n4 << 2) + tid; i < V; i += NT) {
        float e = expf(xrow[i] / t - m);
        unsigned eb = __float_as_uint(e);
        if (eb >= thrkey) {
            float p = e / denom;
            unsigned pos = atomicAdd(&s_cnt, 1u);
            if (pos < CAND_MAX)
                cand[pos] = ((unsigned long long)__float_as_uint(p) << 32)
                          | (unsigned)(~(unsigned)i);
        }
    }
    __syncthreads();

    int n = (int)s_cnt; if (n > CAND_MAX) n = CAND_MAX;
    int n2 = 1; while (n2 < n) n2 <<= 1;
    for (int i = n + tid; i < n2; i += NT) cand[i] = 0ULL;
    __syncthreads();

    // ---------------- Bitonic sort, descending by (p_bits, ~idx) ----------------
    for (int k = 2; k <= n2; k <<= 1) {
        for (int j = k >> 1; j > 0; j >>= 1) {
            for (int i = tid; i < n2; i += NT) {
                int ixj = i ^ j;
                if (ixj > i) {
                    unsigned long long a = cand[i], b = cand[ixj];
                    bool sw = ((i & k) == 0) ? (a < b) : (a > b);
                    if (sw) { cand[i] = b; cand[ixj] = a; }
                }
            }
            __syncthreads();
        }
    }

    // ---------------- Masks + inverse-CDF sampling (thread 0, exact rounding) ---
    if (tid == 0) {
        const float topp = topps[row];
        const float minp = minps[row];
        const float uu = us[row];
        int tk = topks[row];
        if (tk > n) tk = n;
        if (tk > NBINS) tk = NBINS;      // p2buf capacity guard (top_k < 1024 anyway)

        const uint2* ch = (const uint2*)cand;    // .y = p bits, .x = ~idx
        float p0 = __uint_as_float(ch[0].y);
        float thr = p0 * minp;
        float* p2buf = (float*)hist;             // reuse: 1024 floats

        float cum = 0.f, total = 0.f;
        for (int i = 0; i < tk; ++i) {
            float p = __uint_as_float(ch[i].y);
            cum = cum + p;
            float excl = cum - p;                // replicate (cumsum - p) rounding
            float p1 = (excl <= topp) ? p : 0.f;
            float v = (p1 >= thr) ? p1 : 0.f;
            p2buf[i] = v;
            total += v;
        }
        float target = uu * total;
        float cdf = 0.f;
        int sel = -1;
        for (int i = 0; i < tk; ++i) {
            cdf += p2buf[i];
            if (cdf > target) { sel = i; break; }
        }
        if (sel < 0) sel = 0;                    // argmax of all-False -> 0
        out[row] = (int)(~ch[sel].x);
    }
}

extern "C" void kernel_launch(void* const* d_in, const int* in_sizes, int n_in,
                              void* d_out, int out_size, void* d_ws, size_t ws_size,
                              hipStream_t stream) {
    const float* logits = (const float*)d_in[0];
    const float* temps  = (const float*)d_in[1];
    const float* minps  = (const float*)d_in[2];
    const float* topps  = (const float*)d_in[3];
    const int*   topks  = (const int*)d_in[4];
    const float* us     = (const float*)d_in[5];
    int B = in_sizes[1];
    int V = in_sizes[0] / B;
    int* outp = (int*)d_out;
    sampler_kernel<<<dim3(B), dim3(NT), 0, stream>>>(
        logits, temps, minps, topps, topks, us, outp, V);
}

// Round 2
// 197.066 us; speedup vs baseline: 1.1680x; 1.1680x over previous
//
#include <hip/hip_runtime.h>
#include <hip/hip_bf16.h>
#include <stdint.h>

typedef unsigned long long u64;

#define S 16            // slices per row
#define NB 8192         // histogram bins = top 13 bits of monotone float key
#define KSHIFT 19       // 32-13
#define KMARGIN 1152    // >= max top_k (1023) + tie-safety margin
#define CAND_MAX 4096   // global per-row candidate capacity
#define LCAP 2048       // per-block (per-slice) candidate capacity
#define NT1 256
#define NT2 256
#define NT4 1024

__device__ __forceinline__ unsigned fkey(float x) {
    unsigned u = __float_as_uint(x);
    return ((int)u < 0) ? ~u : (u | 0x80000000u);
}

// ---------------- K1: per-slice max + bit-key histogram ----------------
__global__ __launch_bounds__(NT1) void k_hist(
    const float* __restrict__ logits, float* __restrict__ gmax,
    unsigned* __restrict__ ghist, int V, int slen)
{
    const int s = blockIdx.x, b = blockIdx.y, tid = threadIdx.x;
    __shared__ unsigned h[NB];
    __shared__ float red[NT1 / 64];
    for (int i = tid; i < NB; i += NT1) h[i] = 0u;
    __syncthreads();

    const float* xrow = logits + (size_t)b * (size_t)V;
    const int beg = s * slen, end = min(V, beg + slen);
    const float4* x4 = (const float4*)xrow;
    const int beg4 = beg >> 2, end4 = end >> 2;

    float lmax = -INFINITY;
    for (int i = beg4 + tid; i < end4; i += NT1) {
        float4 v = x4[i];
        lmax = fmaxf(lmax, fmaxf(fmaxf(v.x, v.y), fmaxf(v.z, v.w)));
        atomicAdd(&h[fkey(v.x) >> KSHIFT], 1u);
        atomicAdd(&h[fkey(v.y) >> KSHIFT], 1u);
        atomicAdd(&h[fkey(v.z) >> KSHIFT], 1u);
        atomicAdd(&h[fkey(v.w) >> KSHIFT], 1u);
    }
    for (int i = max(beg, end4 << 2) + tid; i < end; i += NT1) {
        float x = xrow[i];
        lmax = fmaxf(lmax, x);
        atomicAdd(&h[fkey(x) >> KSHIFT], 1u);
    }

    for (int off = 32; off > 0; off >>= 1) lmax = fmaxf(lmax, __shfl_xor(lmax, off));
    if ((tid & 63) == 0) red[tid >> 6] = lmax;
    __syncthreads();
    if (tid == 0) {
        float r = red[0];
        for (int w = 1; w < NT1 / 64; ++w) r = fmaxf(r, red[w]);
        gmax[b * S + s] = r;
    }
    unsigned* gh = ghist + (size_t)b * NB;
    for (int i = tid; i < NB; i += NT1)
        if (h[i]) atomicAdd(&gh[i], h[i]);
}

// ---------------- Kt: row max -> m, histogram -> bit threshold ----------------
__global__ __launch_bounds__(64) void k_thr(
    const float* __restrict__ gmax, const float* __restrict__ temps,
    const unsigned* __restrict__ ghist, float* __restrict__ gm,
    unsigned* __restrict__ gthr)
{
    const int b = blockIdx.x, lane = threadIdx.x;
    float v = (lane < S) ? gmax[b * S + lane] : -INFINITY;
    for (int off = 32; off > 0; off >>= 1) v = fmaxf(v, __shfl_xor(v, off));

    const unsigned* h = ghist + (size_t)b * NB;
    const int CH = NB / 64;          // 128 bins per lane
    const int base = lane * CH;
    unsigned c = 0;
    for (int j = 0; j < CH; ++j) c += h[base + j];
    unsigned tsuf = c;
    for (int off = 1; off < 64; off <<= 1) {
        unsigned o = __shfl_down(tsuf, off);
        if (lane + off < 64) tsuf += o;
    }
    unsigned long long mask = __ballot(tsuf >= (unsigned)KMARGIN);
    int lstar = 63 - __builtin_clzll(mask);
    unsigned above = __shfl(tsuf, (lstar + 1) & 63);
    if (lstar == 63) above = 0u;
    if (lane == 0) {
        unsigned run = above;
        int thrbin = lstar * CH;
        for (int bb = lstar * CH + CH - 1; bb >= lstar * CH; --bb) {
            run += h[bb];
            if (run >= (unsigned)KMARGIN) { thrbin = bb; break; }
        }
        gthr[b] = (unsigned)thrbin << KSHIFT;
        gm[b] = v / temps[b];        // = max(round(x_i/t)) by monotone rounding
    }
}

// ---------------- K2: exp partial sums + candidate collection ----------------
__global__ __launch_bounds__(NT2) void k_sum_collect(
    const float* __restrict__ logits, const float* __restrict__ temps,
    const float* __restrict__ gm, const unsigned* __restrict__ gthr,
    float* __restrict__ gsum, u64* __restrict__ gcand,
    unsigned* __restrict__ gcnt, int V, int slen)
{
    const int s = blockIdx.x, b = blockIdx.y, tid = threadIdx.x;
    __shared__ u64 buf[LCAP];
    __shared__ unsigned s_cnt, s_base;
    __shared__ float red[NT2 / 64];
    if (tid == 0) s_cnt = 0u;
    __syncthreads();

    const float t = temps[b], m = gm[b];
    const unsigned thr = gthr[b];
    const float* xrow = logits + (size_t)b * (size_t)V;
    const int beg = s * slen, end = min(V, beg + slen);
    const float4* x4 = (const float4*)xrow;
    const int beg4 = beg >> 2, end4 = end >> 2;

    float lsum = 0.f;
    for (int i = beg4 + tid; i < end4; i += NT2) {
        float4 v = x4[i];
        float e0 = expf(v.x / t - m), e1 = expf(v.y / t - m);
        float e2 = expf(v.z / t - m), e3 = expf(v.w / t - m);
        lsum += e0; lsum += e1; lsum += e2; lsum += e3;
        int i0 = i << 2;
        if (fkey(v.x) >= thr) { unsigned p = atomicAdd(&s_cnt, 1u); if (p < LCAP) buf[p] = ((u64)__float_as_uint(e0) << 32) | (unsigned)~(unsigned)(i0    ); }
        if (fkey(v.y) >= thr) { unsigned p = atomicAdd(&s_cnt, 1u); if (p < LCAP) buf[p] = ((u64)__float_as_uint(e1) << 32) | (unsigned)~(unsigned)(i0 + 1); }
        if (fkey(v.z) >= thr) { unsigned p = atomicAdd(&s_cnt, 1u); if (p < LCAP) buf[p] = ((u64)__float_as_uint(e2) << 32) | (unsigned)~(unsigned)(i0 + 2); }
        if (fkey(v.w) >= thr) { unsigned p = atomicAdd(&s_cnt, 1u); if (p < LCAP) buf[p] = ((u64)__float_as_uint(e3) << 32) | (unsigned)~(unsigned)(i0 + 3); }
    }
    for (int i = max(beg, end4 << 2) + tid; i < end; i += NT2) {
        float x = xrow[i];
        float e = expf(x / t - m);
        lsum += e;
        if (fkey(x) >= thr) { unsigned p = atomicAdd(&s_cnt, 1u); if (p < LCAP) buf[p] = ((u64)__float_as_uint(e) << 32) | (unsigned)~(unsigned)i; }
    }

    for (int off = 32; off > 0; off >>= 1) lsum += __shfl_xor(lsum, off);
    if ((tid & 63) == 0) red[tid >> 6] = lsum;
    __syncthreads();
    if (tid == 0) {
        float r = 0.f;
        for (int w = 0; w < NT2 / 64; ++w) r += red[w];
        gsum[b * S + s] = r;
        unsigned cnt = min(s_cnt, (unsigned)LCAP);
        s_base = atomicAdd(&gcnt[b], cnt);
        s_cnt = cnt;
    }
    __syncthreads();
    const unsigned cnt = s_cnt, base = s_base;
    u64* dst = gcand + (size_t)b * CAND_MAX;
    for (unsigned i = tid; i < cnt; i += NT2) {
        unsigned p = base + i;
        if (p < CAND_MAX) dst[p] = buf[i];
    }
}

// ---------------- K4: p = e/denom, bitonic sort, masks + inverse-CDF ----------------
__global__ __launch_bounds__(NT4) void k_finish(
    const u64* __restrict__ gcand, const unsigned* __restrict__ gcnt,
    const float* __restrict__ gsum, const float* __restrict__ minps,
    const float* __restrict__ topps, const int* __restrict__ topks,
    const float* __restrict__ us, int* __restrict__ out)
{
    const int b = blockIdx.x, tid = threadIdx.x;
    __shared__ u64 cand[CAND_MAX];
    __shared__ float s_denom;
    if (tid == 0) {
        float d = 0.f;
        for (int j = 0; j < S; ++j) d += gsum[b * S + j];
        s_denom = d;
    }
    __syncthreads();
    const float denom = s_denom;
    int n = (int)min(gcnt[b], (unsigned)CAND_MAX);
    const u64* src = gcand + (size_t)b * CAND_MAX;
    for (int i = tid; i < n; i += NT4) {
        u64 w = src[i];
        float e = __uint_as_float((unsigned)(w >> 32));
        float p = e / denom;
        cand[i] = ((u64)__float_as_uint(p) << 32) | (unsigned)w;
    }
    int n2 = 1; while (n2 < n) n2 <<= 1;
    for (int i = n + tid; i < n2; i += NT4) cand[i] = 0ULL;
    __syncthreads();

    for (int k = 2; k <= n2; k <<= 1) {
        for (int j = k >> 1; j > 0; j >>= 1) {
            for (int i = tid; i < n2; i += NT4) {
                int ixj = i ^ j;
                if (ixj > i) {
                    u64 a = cand[i], bb = cand[ixj];
                    bool sw = ((i & k) == 0) ? (a < bb) : (a > bb);
                    if (sw) { cand[i] = bb; cand[ixj] = a; }
                }
            }
            __syncthreads();
        }
    }

    if (tid == 0) {
        const float topp = topps[b], minp = minps[b], uu = us[b];
        int tk = topks[b];
        if (tk > n) tk = n;
        float p0 = __uint_as_float((unsigned)(cand[0] >> 32));
        float thrmp = p0 * minp;

        float cum = 0.f, total = 0.f;
        for (int i = 0; i < tk; ++i) {
            float p = __uint_as_float((unsigned)(cand[i] >> 32));
            cum = cum + p;
            float excl = cum - p;                 // replicate (cumsum - p) rounding
            float p1 = (excl <= topp) ? p : 0.f;
            float v = (p1 >= thrmp) ? p1 : 0.f;
            total += v;
        }
        float target = uu * total;
        float cdf = 0.f; int sel = -1;
        cum = 0.f;
        for (int i = 0; i < tk; ++i) {
            float p = __uint_as_float((unsigned)(cand[i] >> 32));
            cum = cum + p;
            float excl = cum - p;
            float p1 = (excl <= topp) ? p : 0.f;
            float v = (p1 >= thrmp) ? p1 : 0.f;
            cdf += v;
            if (cdf > target) { sel = i; break; }
        }
        if (sel < 0) sel = 0;
        out[b] = (int)~(unsigned)cand[sel];
    }
}

// ---------------- Fallback: monolithic single kernel (round-1, passed) ----------------
#define FNT 512
#define FNBINS 1024
#define FKMARGIN 1224
__global__ __launch_bounds__(FNT) void sampler_mono(
    const float* __restrict__ logits, const float* __restrict__ temps,
    const float* __restrict__ minps, const float* __restrict__ topps,
    const int* __restrict__ topks, const float* __restrict__ us,
    int* __restrict__ out, int V)
{
    const int row = blockIdx.x;
    const int tid = threadIdx.x;
    const float t = temps[row];
    __shared__ unsigned int hist[FNBINS];
    __shared__ u64 cand[CAND_MAX];
    __shared__ float red[FNT / 64];
    __shared__ float s_m, s_denom;
    __shared__ unsigned s_thr, s_cnt;
    for (int i = tid; i < FNBINS; i += FNT) hist[i] = 0u;
    if (tid == 0) s_cnt = 0u;
    const float* xrow = logits + (size_t)row * (size_t)V;
    const int n4 = V >> 2;
    const float4* x4 = (const float4*)xrow;
    float lmax = -INFINITY;
    for (int i = tid; i < n4; i += FNT) {
        float4 v = x4[i];
        lmax = fmaxf(lmax, fmaxf(fmaxf(v.x, v.y), fmaxf(v.z, v.w)));
    }
    for (int i = (n4 << 2) + tid; i < V; i += FNT) lmax = fmaxf(lmax, xrow[i]);
    for (int off = 32; off > 0; off >>= 1) lmax = fmaxf(lmax, __shfl_xor(lmax, off));
    if ((tid & 63) == 0) red[tid >> 6] = lmax;
    __syncthreads();
    if (tid == 0) {
        float r = red[0];
        for (int w = 1; w < FNT / 64; ++w) r = fmaxf(r, red[w]);
        s_m = r / t;
    }
    __syncthreads();
    const float m = s_m;
    float lsum = 0.f;
    for (int i = tid; i < n4; i += FNT) {
        float4 v = x4[i];
        float e0 = expf(v.x / t - m), e1 = expf(v.y / t - m);
        float e2 = expf(v.z / t - m), e3 = expf(v.w / t - m);
        lsum += e0; lsum += e1; lsum += e2; lsum += e3;
        atomicAdd(&hist[__float_as_uint(e0) >> 20], 1u);
        atomicAdd(&hist[__float_as_uint(e1) >> 20], 1u);
        atomicAdd(&hist[__float_as_uint(e2) >> 20], 1u);
        atomicAdd(&hist[__float_as_uint(e3) >> 20], 1u);
    }
    for (int i = (n4 << 2) + tid; i < V; i += FNT) {
        float e = expf(xrow[i] / t - m);
        lsum += e;
        atomicAdd(&hist[__float_as_uint(e) >> 20], 1u);
    }
    for (int off = 32; off > 0; off >>= 1) lsum += __shfl_xor(lsum, off);
    if ((tid & 63) == 0) red[tid >> 6] = lsum;
    __syncthreads();
    if (tid == 0) {
        float r = 0.f;
        for (int w = 0; w < FNT / 64; ++w) r += red[w];
        s_denom = r;
    }
    __syncthreads();
    const float denom = s_denom;
    if (tid < 64) {
        const int lane = tid;
        const int CH = FNBINS / 64;
        const int base = lane * CH;
        unsigned c = 0;
        #pragma unroll
        for (int j = 0; j < CH; ++j) c += hist[base + j];
        unsigned tsuf = c;
        #pragma unroll
        for (int off = 1; off < 64; off <<= 1) {
            unsigned o = __shfl_down(tsuf, off);
            if (lane + off < 64) tsuf += o;
        }
        unsigned long long mask = __ballot(tsuf >= (unsigned)FKMARGIN);
        int lstar = 63 - __builtin_clzll(mask);
        unsigned above = __shfl(tsuf, (lstar + 1) & 63);
        if (lstar == 63) above = 0u;
        if (lane == 0) {
            unsigned run = above;
            int thrbin = lstar * CH;
            for (int bb = lstar * CH + CH - 1; bb >= lstar * CH; --bb) {
                run += hist[bb];
                if (run >= (unsigned)FKMARGIN) { thrbin = bb; break; }
            }
            s_thr = (unsigned)thrbin << 20;
        }
    }
    __syncthreads();
    const unsigned thrkey = s_thr;
    for (int i = tid; i < n4; i += FNT) {
        float4 v = x4[i];
        float e[4] = { expf(v.x / t - m), expf(v.y / t - m),
                       expf(v.z / t - m), expf(v.w / t - m) };
        #pragma unroll
        for (int c = 0; c < 4; ++c) {
            unsigned eb = __float_as_uint(e[c]);
            if (eb >= thrkey) {
                float p = e[c] / denom;
                unsigned pos = atomicAdd(&s_cnt, 1u);
                if (pos < CAND_MAX)
                    cand[pos] = ((u64)__float_as_uint(p) << 32) | (unsigned)(~(unsigned)((i << 2) + c));
            }
        }
    }
    for (int i = (n4 << 2) + tid; i < V; i += FNT) {
        float e = expf(xrow[i] / t - m);
        if (__float_as_uint(e) >= thrkey) {
            float p = e / denom;
            unsigned pos = atomicAdd(&s_cnt, 1u);
            if (pos < CAND_MAX)
                cand[pos] = ((u64)__float_as_uint(p) << 32) | (unsigned)(~(unsigned)i);
        }
    }
    __syncthreads();
    int n = (int)s_cnt; if (n > CAND_MAX) n = CAND_MAX;
    int n2 = 1; while (n2 < n) n2 <<= 1;
    for (int i = n + tid; i < n2; i += FNT) cand[i] = 0ULL;
    __syncthreads();
    for (int k = 2; k <= n2; k <<= 1) {
        for (int j = k >> 1; j > 0; j >>= 1) {
            for (int i = tid; i < n2; i += FNT) {
                int ixj = i ^ j;
                if (ixj > i) {
                    u64 a = cand[i], bb = cand[ixj];
                    bool sw = ((i & k) == 0) ? (a < bb) : (a > bb);
                    if (sw) { cand[i] = bb; cand[ixj] = a; }
                }
            }
            __syncthreads();
        }
    }
    if (tid == 0) {
        const float topp = topps[row], minp = minps[row], uu = us[row];
        int tk = topks[row];
        if (tk > n) tk = n;
        float p0 = __uint_as_float((unsigned)(cand[0] >> 32));
        float thrmp = p0 * minp;
        float cum = 0.f, total = 0.f;
        for (int i = 0; i < tk; ++i) {
            float p = __uint_as_float((unsigned)(cand[i] >> 32));
            cum = cum + p;
            float excl = cum - p;
            float p1 = (excl <= topp) ? p : 0.f;
            float v = (p1 >= thrmp) ? p1 : 0.f;
            total += v;
        }
        float target = uu * total;
        float cdf = 0.f; int sel = -1;
        cum = 0.f;
        for (int i = 0; i < tk; ++i) {
            float p = __uint_as_float((unsigned)(cand[i] >> 32));
            cum = cum + p;
            float excl = cum - p;
            float p1 = (excl <= topp) ? p : 0.f;
            float v = (p1 >= thrmp) ? p1 : 0.f;
            cdf += v;
            if (cdf > target) { sel = i; break; }
        }
        if (sel < 0) sel = 0;
        out[row] = (int)~(unsigned)cand[sel];
    }
}

extern "C" void kernel_launch(void* const* d_in, const int* in_sizes, int n_in,
                              void* d_out, int out_size, void* d_ws, size_t ws_size,
                              hipStream_t stream) {
    const float* logits = (const float*)d_in[0];
    const float* temps  = (const float*)d_in[1];
    const float* minps  = (const float*)d_in[2];
    const float* topps  = (const float*)d_in[3];
    const int*   topks  = (const int*)d_in[4];
    const float* us     = (const float*)d_in[5];
    const int B = in_sizes[1];
    const int V = in_sizes[0] / B;
    int* outp = (int*)d_out;

    const int slen = (((V + S - 1) / S) + 3) & ~3;   // slice length, mult of 4

    size_t need = 0;
    const size_t off_cand = need; need += (size_t)B * CAND_MAX * sizeof(u64);
    const size_t off_hist = need; need += (size_t)B * NB * sizeof(unsigned);
    const size_t off_cnt  = need; need += (size_t)B * sizeof(unsigned);
    const size_t off_max  = need; need += (size_t)B * S * sizeof(float);
    const size_t off_sum  = need; need += (size_t)B * S * sizeof(float);
    const size_t off_m    = need; need += (size_t)B * sizeof(float);
    const size_t off_thr  = need; need += (size_t)B * sizeof(unsigned);

    if (ws_size < need) {
        sampler_mono<<<dim3(B), dim3(FNT), 0, stream>>>(
            logits, temps, minps, topps, topks, us, outp, V);
        return;
    }

    char* w = (char*)d_ws;
    u64*      gcand = (u64*)(w + off_cand);
    unsigned* ghist = (unsigned*)(w + off_hist);
    unsigned* gcnt  = (unsigned*)(w + off_cnt);
    float*    gmax  = (float*)(w + off_max);
    float*    gsum  = (float*)(w + off_sum);
    float*    gm    = (float*)(w + off_m);
    unsigned* gthr  = (unsigned*)(w + off_thr);

    // zero ghist + gcnt (contiguous)
    hipMemsetAsync(ghist, 0, (size_t)B * NB * sizeof(unsigned) + (size_t)B * sizeof(unsigned), stream);

    k_hist<<<dim3(S, B), dim3(NT1), 0, stream>>>(logits, gmax, ghist, V, slen);
    k_thr<<<dim3(B), dim3(64), 0, stream>>>(gmax, temps, ghist, gm, gthr);
    k_sum_collect<<<dim3(S, B), dim3(NT2), 0, stream>>>(
        logits, temps, gm, gthr, gsum, gcand, gcnt, V, slen);
    k_finish<<<dim3(B), dim3(NT4), 0, stream>>>(
        gcand, gcnt, gsum, minps, topps, topks, us, outp);
}

// Round 5
// 95.353 us; speedup vs baseline: 2.4138x; 2.0667x over previous
//
#include <hip/hip_runtime.h>
#include <hip/hip_bf16.h>
#include <stdint.h>

typedef unsigned long long u64;

#define S 16            // slices per row
#define NB 8192         // histogram bins = top 13 bits of monotone float key
#define KSHIFT 19       // 32-13
#define KMARGIN 1152    // >= max top_k (1023) + tie-safety margin
#define CAND_MAX 4096   // global per-row candidate capacity
#define LCAP 2048       // per-block (per-slice) candidate capacity
#define NT1 256
#define NT2 256
#define NT4 1024
#define NW4 (NT4 / 64)

__device__ __forceinline__ unsigned fkey(float x) {
    unsigned u = __float_as_uint(x);
    return ((int)u < 0) ? ~u : (u | 0x80000000u);
}

// ---------------- K1: per-slice max + bit-key histogram ----------------
__global__ __launch_bounds__(NT1) void k_hist(
    const float* __restrict__ logits, float* __restrict__ gmax,
    unsigned* __restrict__ ghist, int V, int slen)
{
    const int s = blockIdx.x, b = blockIdx.y, tid = threadIdx.x;
    __shared__ unsigned h[NB];
    __shared__ float red[NT1 / 64];
    for (int i = tid; i < NB; i += NT1) h[i] = 0u;
    __syncthreads();

    const float* xrow = logits + (size_t)b * (size_t)V;
    const int beg = s * slen, end = min(V, beg + slen);
    const float4* x4 = (const float4*)xrow;
    const int beg4 = beg >> 2, end4 = end >> 2;

    float lmax = -INFINITY;
    for (int i = beg4 + tid; i < end4; i += NT1) {
        float4 v = x4[i];
        lmax = fmaxf(lmax, fmaxf(fmaxf(v.x, v.y), fmaxf(v.z, v.w)));
        atomicAdd(&h[fkey(v.x) >> KSHIFT], 1u);
        atomicAdd(&h[fkey(v.y) >> KSHIFT], 1u);
        atomicAdd(&h[fkey(v.z) >> KSHIFT], 1u);
        atomicAdd(&h[fkey(v.w) >> KSHIFT], 1u);
    }
    for (int i = max(beg, end4 << 2) + tid; i < end; i += NT1) {
        float x = xrow[i];
        lmax = fmaxf(lmax, x);
        atomicAdd(&h[fkey(x) >> KSHIFT], 1u);
    }

    for (int off = 32; off > 0; off >>= 1) lmax = fmaxf(lmax, __shfl_xor(lmax, off));
    if ((tid & 63) == 0) red[tid >> 6] = lmax;
    __syncthreads();
    if (tid == 0) {
        float r = red[0];
        for (int w = 1; w < NT1 / 64; ++w) r = fmaxf(r, red[w]);
        gmax[b * S + s] = r;
    }
    unsigned* gh = ghist + (size_t)b * NB;
    for (int i = tid; i < NB; i += NT1)
        if (h[i]) atomicAdd(&gh[i], h[i]);
}

// ---------------- Kt: row max -> m, histogram -> bit threshold ----------------
__global__ __launch_bounds__(64) void k_thr(
    const float* __restrict__ gmax, const float* __restrict__ temps,
    const unsigned* __restrict__ ghist, float* __restrict__ gm,
    unsigned* __restrict__ gthr)
{
    const int b = blockIdx.x, lane = threadIdx.x;
    float v = (lane < S) ? gmax[b * S + lane] : -INFINITY;
    for (int off = 32; off > 0; off >>= 1) v = fmaxf(v, __shfl_xor(v, off));

    const unsigned* h = ghist + (size_t)b * NB;
    const int CH = NB / 64;          // 128 bins per lane
    const int base = lane * CH;
    unsigned c = 0;
    for (int j = 0; j < CH; ++j) c += h[base + j];
    unsigned tsuf = c;
    for (int off = 1; off < 64; off <<= 1) {
        unsigned o = __shfl_down(tsuf, off);
        if (lane + off < 64) tsuf += o;
    }
    unsigned long long mask = __ballot(tsuf >= (unsigned)KMARGIN);
    int lstar = 63 - __builtin_clzll(mask);
    unsigned above = __shfl(tsuf, (lstar + 1) & 63);
    if (lstar == 63) above = 0u;
    if (lane == 0) {
        unsigned run = above;
        int thrbin = lstar * CH;
        for (int bb = lstar * CH + CH - 1; bb >= lstar * CH; --bb) {
            run += h[bb];
            if (run >= (unsigned)KMARGIN) { thrbin = bb; break; }
        }
        gthr[b] = (unsigned)thrbin << KSHIFT;
        gm[b] = v / temps[b];        // = max(round(x_i/t)) by monotone rounding
    }
}

// ---------------- K2: exp partial sums + candidate collection ----------------
__global__ __launch_bounds__(NT2) void k_sum_collect(
    const float* __restrict__ logits, const float* __restrict__ temps,
    const float* __restrict__ gm, const unsigned* __restrict__ gthr,
    float* __restrict__ gsum, u64* __restrict__ gcand,
    unsigned* __restrict__ gcnt, int V, int slen)
{
    const int s = blockIdx.x, b = blockIdx.y, tid = threadIdx.x;
    __shared__ u64 buf[LCAP];
    __shared__ unsigned s_cnt, s_base;
    __shared__ float red[NT2 / 64];
    if (tid == 0) s_cnt = 0u;
    __syncthreads();

    const float t = temps[b], m = gm[b];
    const unsigned thr = gthr[b];
    const float* xrow = logits + (size_t)b * (size_t)V;
    const int beg = s * slen, end = min(V, beg + slen);
    const float4* x4 = (const float4*)xrow;
    const int beg4 = beg >> 2, end4 = end >> 2;

    float lsum = 0.f;
    for (int i = beg4 + tid; i < end4; i += NT2) {
        float4 v = x4[i];
        float e0 = expf(v.x / t - m), e1 = expf(v.y / t - m);
        float e2 = expf(v.z / t - m), e3 = expf(v.w / t - m);
        lsum += e0; lsum += e1; lsum += e2; lsum += e3;
        int i0 = i << 2;
        if (fkey(v.x) >= thr) { unsigned p = atomicAdd(&s_cnt, 1u); if (p < LCAP) buf[p] = ((u64)__float_as_uint(e0) << 32) | (unsigned)~(unsigned)(i0    ); }
        if (fkey(v.y) >= thr) { unsigned p = atomicAdd(&s_cnt, 1u); if (p < LCAP) buf[p] = ((u64)__float_as_uint(e1) << 32) | (unsigned)~(unsigned)(i0 + 1); }
        if (fkey(v.z) >= thr) { unsigned p = atomicAdd(&s_cnt, 1u); if (p < LCAP) buf[p] = ((u64)__float_as_uint(e2) << 32) | (unsigned)~(unsigned)(i0 + 2); }
        if (fkey(v.w) >= thr) { unsigned p = atomicAdd(&s_cnt, 1u); if (p < LCAP) buf[p] = ((u64)__float_as_uint(e3) << 32) | (unsigned)~(unsigned)(i0 + 3); }
    }
    for (int i = max(beg, end4 << 2) + tid; i < end; i += NT2) {
        float x = xrow[i];
        float e = expf(x / t - m);
        lsum += e;
        if (fkey(x) >= thr) { unsigned p = atomicAdd(&s_cnt, 1u); if (p < LCAP) buf[p] = ((u64)__float_as_uint(e) << 32) | (unsigned)~(unsigned)i; }
    }

    for (int off = 32; off > 0; off >>= 1) lsum += __shfl_xor(lsum, off);
    if ((tid & 63) == 0) red[tid >> 6] = lsum;
    __syncthreads();
    if (tid == 0) {
        float r = 0.f;
        for (int w = 0; w < NT2 / 64; ++w) r += red[w];
        gsum[b * S + s] = r;
        unsigned cnt = min(s_cnt, (unsigned)LCAP);
        s_base = atomicAdd(&gcnt[b], cnt);
        s_cnt = cnt;
    }
    __syncthreads();
    const unsigned cnt = s_cnt, base = s_base;
    u64* dst = gcand + (size_t)b * CAND_MAX;
    for (unsigned i = tid; i < cnt; i += NT2) {
        unsigned p = base + i;
        if (p < CAND_MAX) dst[p] = buf[i];
    }
}

// ---------------- K4: p = e/denom, bitonic sort, parallel masks + inverse-CDF ----
__global__ __launch_bounds__(NT4) void k_finish(
    const u64* __restrict__ gcand, const unsigned* __restrict__ gcnt,
    const float* __restrict__ gsum, const float* __restrict__ minps,
    const float* __restrict__ topps, const int* __restrict__ topks,
    const float* __restrict__ us, int* __restrict__ out)
{
    const int b = blockIdx.x, tid = threadIdx.x;
    __shared__ u64 cand[CAND_MAX];
    __shared__ float s_denom;
    __shared__ float wsum[NW4];
    __shared__ unsigned wfirst[NW4];
    if (tid == 0) {
        float d = 0.f;
        for (int j = 0; j < S; ++j) d += gsum[b * S + j];
        s_denom = d;
    }
    __syncthreads();
    const float denom = s_denom;
    int n = (int)min(gcnt[b], (unsigned)CAND_MAX);
    const u64* src = gcand + (size_t)b * CAND_MAX;
    for (int i = tid; i < n; i += NT4) {
        u64 w = src[i];
        float e = __uint_as_float((unsigned)(w >> 32));
        float p = e / denom;
        cand[i] = ((u64)__float_as_uint(p) << 32) | (unsigned)w;
    }
    int n2 = 1; while (n2 < n) n2 <<= 1;
    for (int i = n + tid; i < n2; i += NT4) cand[i] = 0ULL;
    __syncthreads();

    // bitonic sort, descending by (p_bits, ~idx)
    for (int k = 2; k <= n2; k <<= 1) {
        for (int j = k >> 1; j > 0; j >>= 1) {
            for (int i = tid; i < n2; i += NT4) {
                int ixj = i ^ j;
                if (ixj > i) {
                    u64 a = cand[i], bb = cand[ixj];
                    bool sw = ((i & k) == 0) ? (a < bb) : (a > bb);
                    if (sw) { cand[i] = bb; cand[ixj] = a; }
                }
            }
            __syncthreads();
        }
    }

    // ---- parallel epilogue: thread i owns sorted element i (i < tk <= 1023) ----
    const int lane = tid & 63, wv = tid >> 6;
    const float topp = topps[b], minp = minps[b], uu = us[b];
    int tk = topks[b];
    if (tk > n) tk = n;
    if (tk > NT4) tk = NT4;          // top_k < 1024 by problem spec

    float p = 0.f;
    if (tid < tk) p = __uint_as_float((unsigned)(cand[tid] >> 32));

    // inclusive scan of p -> cum
    float c = p;
    #pragma unroll
    for (int off = 1; off < 64; off <<= 1) {
        float o = __shfl_up(c, off);
        if (lane >= off) c += o;
    }
    if (lane == 63) wsum[wv] = c;
    __syncthreads();
    if (tid < 64) {
        float sv = (tid < NW4) ? wsum[tid] : 0.f;
        #pragma unroll
        for (int off = 1; off < NW4; off <<= 1) {
            float o = __shfl_up(sv, off);
            if (tid >= off) sv += o;
        }
        if (tid < NW4) wsum[tid] = sv;
    }
    __syncthreads();
    float cum = c + ((wv > 0) ? wsum[wv - 1] : 0.f);
    float excl = cum - p;                       // replicate (cumsum - p) rounding shape
    float p0 = __uint_as_float((unsigned)(cand[0] >> 32));
    float thrmp = p0 * minp;
    float p1v = (excl <= topp) ? p : 0.f;
    float v = (p1v >= thrmp) ? p1v : 0.f;
    __syncthreads();                            // done reading wsum from scan 1

    // inclusive scan of v -> cdf ; total = grand sum
    float cv = v;
    #pragma unroll
    for (int off = 1; off < 64; off <<= 1) {
        float o = __shfl_up(cv, off);
        if (lane >= off) cv += o;
    }
    if (lane == 63) wsum[wv] = cv;
    __syncthreads();
    if (tid < 64) {
        float sv = (tid < NW4) ? wsum[tid] : 0.f;
        #pragma unroll
        for (int off = 1; off < NW4; off <<= 1) {
            float o = __shfl_up(sv, off);
            if (tid >= off) sv += o;
        }
        if (tid < NW4) wsum[tid] = sv;
    }
    __syncthreads();
    float cdf = cv + ((wv > 0) ? wsum[wv - 1] : 0.f);
    float total = wsum[NW4 - 1];
    float target = uu * total;

    bool hit = (tid < tk) && (cdf > target);
    unsigned long long mk = __ballot(hit);
    if (lane == 0) wfirst[wv] = mk ? (unsigned)__builtin_ctzll(mk) : 0xFFFFFFFFu;
    __syncthreads();
    if (tid == 0) {
        int sel = -1;
        for (int w = 0; w < NW4; ++w)
            if (wfirst[w] != 0xFFFFFFFFu) { sel = w * 64 + (int)wfirst[w]; break; }
        if (sel < 0) sel = 0;                   // argmax of all-False -> 0
        out[b] = (int)~(unsigned)cand[sel];
    }
}

// ---------------- Fallback: monolithic single kernel (round-1, passed) ----------------
#define FNT 512
#define FNBINS 1024
#define FKMARGIN 1224
__global__ __launch_bounds__(FNT) void sampler_mono(
    const float* __restrict__ logits, const float* __restrict__ temps,
    const float* __restrict__ minps, const float* __restrict__ topps,
    const int* __restrict__ topks, const float* __restrict__ us,
    int* __restrict__ out, int V)
{
    const int row = blockIdx.x;
    const int tid = threadIdx.x;
    const float t = temps[row];
    __shared__ unsigned int hist[FNBINS];
    __shared__ u64 cand[CAND_MAX];
    __shared__ float red[FNT / 64];
    __shared__ float s_m, s_denom;
    __shared__ unsigned s_thr, s_cnt;
    for (int i = tid; i < FNBINS; i += FNT) hist[i] = 0u;
    if (tid == 0) s_cnt = 0u;
    const float* xrow = logits + (size_t)row * (size_t)V;
    const int n4 = V >> 2;
    const float4* x4 = (const float4*)xrow;
    float lmax = -INFINITY;
    for (int i = tid; i < n4; i += FNT) {
        float4 v = x4[i];
        lmax = fmaxf(lmax, fmaxf(fmaxf(v.x, v.y), fmaxf(v.z, v.w)));
    }
    for (int i = (n4 << 2) + tid; i < V; i += FNT) lmax = fmaxf(lmax, xrow[i]);
    for (int off = 32; off > 0; off >>= 1) lmax = fmaxf(lmax, __shfl_xor(lmax, off));
    if ((tid & 63) == 0) red[tid >> 6] = lmax;
    __syncthreads();
    if (tid == 0) {
        float r = red[0];
        for (int w = 1; w < FNT / 64; ++w) r = fmaxf(r, red[w]);
        s_m = r / t;
    }
    __syncthreads();
    const float m = s_m;
    float lsum = 0.f;
    for (int i = tid; i < n4; i += FNT) {
        float4 v = x4[i];
        float e0 = expf(v.x / t - m), e1 = expf(v.y / t - m);
        float e2 = expf(v.z / t - m), e3 = expf(v.w / t - m);
        lsum += e0; lsum += e1; lsum += e2; lsum += e3;
        atomicAdd(&hist[__float_as_uint(e0) >> 20], 1u);
        atomicAdd(&hist[__float_as_uint(e1) >> 20], 1u);
        atomicAdd(&hist[__float_as_uint(e2) >> 20], 1u);
        atomicAdd(&hist[__float_as_uint(e3) >> 20], 1u);
    }
    for (int i = (n4 << 2) + tid; i < V; i += FNT) {
        float e = expf(xrow[i] / t - m);
        lsum += e;
        atomicAdd(&hist[__float_as_uint(e) >> 20], 1u);
    }
    for (int off = 32; off > 0; off >>= 1) lsum += __shfl_xor(lsum, off);
    if ((tid & 63) == 0) red[tid >> 6] = lsum;
    __syncthreads();
    if (tid == 0) {
        float r = 0.f;
        for (int w = 0; w < FNT / 64; ++w) r += red[w];
        s_denom = r;
    }
    __syncthreads();
    const float denom = s_denom;
    if (tid < 64) {
        const int lane = tid;
        const int CH = FNBINS / 64;
        const int base = lane * CH;
        unsigned c = 0;
        #pragma unroll
        for (int j = 0; j < CH; ++j) c += hist[base + j];
        unsigned tsuf = c;
        #pragma unroll
        for (int off = 1; off < 64; off <<= 1) {
            unsigned o = __shfl_down(tsuf, off);
            if (lane + off < 64) tsuf += o;
        }
        unsigned long long mask = __ballot(tsuf >= (unsigned)FKMARGIN);
        int lstar = 63 - __builtin_clzll(mask);
        unsigned above = __shfl(tsuf, (lstar + 1) & 63);
        if (lstar == 63) above = 0u;
        if (lane == 0) {
            unsigned run = above;
            int thrbin = lstar * CH;
            for (int bb = lstar * CH + CH - 1; bb >= lstar * CH; --bb) {
                run += hist[bb];
                if (run >= (unsigned)FKMARGIN) { thrbin = bb; break; }
            }
            s_thr = (unsigned)thrbin << 20;
        }
    }
    __syncthreads();
    const unsigned thrkey = s_thr;
    for (int i = tid; i < n4; i += FNT) {
        float4 v = x4[i];
        float e[4] = { expf(v.x / t - m), expf(v.y / t - m),
                       expf(v.z / t - m), expf(v.w / t - m) };
        #pragma unroll
        for (int c = 0; c < 4; ++c) {
            unsigned eb = __float_as_uint(e[c]);
            if (eb >= thrkey) {
                float p = e[c] / denom;
                unsigned pos = atomicAdd(&s_cnt, 1u);
                if (pos < CAND_MAX)
                    cand[pos] = ((u64)__float_as_uint(p) << 32) | (unsigned)(~(unsigned)((i << 2) + c));
            }
        }
    }
    for (int i = (n4 << 2) + tid; i < V; i += FNT) {
        float e = expf(xrow[i] / t - m);
        if (__float_as_uint(e) >= thrkey) {
            float p = e / denom;
            unsigned pos = atomicAdd(&s_cnt, 1u);
            if (pos < CAND_MAX)
                cand[pos] = ((u64)__float_as_uint(p) << 32) | (unsigned)(~(unsigned)i);
        }
    }
    __syncthreads();
    int n = (int)s_cnt; if (n > CAND_MAX) n = CAND_MAX;
    int n2 = 1; while (n2 < n) n2 <<= 1;
    for (int i = n + tid; i < n2; i += FNT) cand[i] = 0ULL;
    __syncthreads();
    for (int k = 2; k <= n2; k <<= 1) {
        for (int j = k >> 1; j > 0; j >>= 1) {
            for (int i = tid; i < n2; i += FNT) {
                int ixj = i ^ j;
                if (ixj > i) {
                    u64 a = cand[i], bb = cand[ixj];
                    bool sw = ((i & k) == 0) ? (a < bb) : (a > bb);
                    if (sw) { cand[i] = bb; cand[ixj] = a; }
                }
            }
            __syncthreads();
        }
    }
    if (tid == 0) {
        const float topp = topps[row], minp = minps[row], uu = us[row];
        int tk = topks[row];
        if (tk > n) tk = n;
        float p0 = __uint_as_float((unsigned)(cand[0] >> 32));
        float thrmp = p0 * minp;
        float cum = 0.f, total = 0.f;
        for (int i = 0; i < tk; ++i) {
            float p = __uint_as_float((unsigned)(cand[i] >> 32));
            cum = cum + p;
            float excl = cum - p;
            float p1 = (excl <= topp) ? p : 0.f;
            float v = (p1 >= thrmp) ? p1 : 0.f;
            total += v;
        }
        float target = uu * total;
        float cdf = 0.f; int sel = -1;
        cum = 0.f;
        for (int i = 0; i < tk; ++i) {
            float p = __uint_as_float((unsigned)(cand[i] >> 32));
            cum = cum + p;
            float excl = cum - p;
            float p1 = (excl <= topp) ? p : 0.f;
            float v = (p1 >= thrmp) ? p1 : 0.f;
            cdf += v;
            if (cdf > target) { sel = i; break; }
        }
        if (sel < 0) sel = 0;
        out[row] = (int)~(unsigned)cand[sel];
    }
}

extern "C" void kernel_launch(void* const* d_in, const int* in_sizes, int n_in,
                              void* d_out, int out_size, void* d_ws, size_t ws_size,
                              hipStream_t stream) {
    const float* logits = (const float*)d_in[0];
    const float* temps  = (const float*)d_in[1];
    const float* minps  = (const float*)d_in[2];
    const float* topps  = (const float*)d_in[3];
    const int*   topks  = (const int*)d_in[4];
    const float* us     = (const float*)d_in[5];
    const int B = in_sizes[1];
    const int V = in_sizes[0] / B;
    int* outp = (int*)d_out;

    const int slen = (((V + S - 1) / S) + 3) & ~3;   // slice length, mult of 4

    size_t need = 0;
    const size_t off_cand = need; need += (size_t)B * CAND_MAX * sizeof(u64);
    const size_t off_hist = need; need += (size_t)B * NB * sizeof(unsigned);
    const size_t off_cnt  = need; need += (size_t)B * sizeof(unsigned);
    const size_t off_max  = need; need += (size_t)B * S * sizeof(float);
    const size_t off_sum  = need; need += (size_t)B * S * sizeof(float);
    const size_t off_m    = need; need += (size_t)B * sizeof(float);
    const size_t off_thr  = need; need += (size_t)B * sizeof(unsigned);

    if (ws_size < need) {
        sampler_mono<<<dim3(B), dim3(FNT), 0, stream>>>(
            logits, temps, minps, topps, topks, us, outp, V);
        return;
    }

    char* w = (char*)d_ws;
    u64*      gcand = (u64*)(w + off_cand);
    unsigned* ghist = (unsigned*)(w + off_hist);
    unsigned* gcnt  = (unsigned*)(w + off_cnt);
    float*    gmax  = (float*)(w + off_max);
    float*    gsum  = (float*)(w + off_sum);
    float*    gm    = (float*)(w + off_m);
    unsigned* gthr  = (unsigned*)(w + off_thr);

    // zero ghist + gcnt (contiguous)
    hipMemsetAsync(ghist, 0, (size_t)B * NB * sizeof(unsigned) + (size_t)B * sizeof(unsigned), stream);

    k_hist<<<dim3(S, B), dim3(NT1), 0, stream>>>(logits, gmax, ghist, V, slen);
    k_thr<<<dim3(B), dim3(64), 0, stream>>>(gmax, temps, ghist, gm, gthr);
    k_sum_collect<<<dim3(S, B), dim3(NT2), 0, stream>>>(
        logits, temps, gm, gthr, gsum, gcand, gcnt, V, slen);
    k_finish<<<dim3(B), dim3(NT4), 0, stream>>>(
        gcand, gcnt, gsum, minps, topps, topks, us, outp);
}